// Round 3
// baseline (704.331 us; speedup 1.0000x reference)
//
#include <hip/hip_runtime.h>
#include <hip/hip_bf16.h>

#define N_ENT  100000
#define N_REL2 1000
#define H      256
#define E_EDGES 320000
#define N_TILES  6250      // N_ENT/16 exactly
#define REL_TILES 64       // ceil(1000/16)=63, pad to 64
#define TILE_SH 4096       // shorts per 16-row tile (16*256)
#define MAXE 256           // max edges per 16-dst tile (mean 51, sigma 7 -> 28 sigma headroom)

typedef unsigned short u16;
typedef short bf16x8 __attribute__((ext_vector_type(8)));
typedef float floatx4 __attribute__((ext_vector_type(4)));

__device__ __forceinline__ u16 f2bf(float f) {
    unsigned x = __float_as_uint(f);
    unsigned r = (x + 0x7fffu + ((x >> 16) & 1u)) >> 16;  // RNE
    return (u16)r;
}

__device__ __forceinline__ ushort4 pack4(float4 v) {
    return make_ushort4(f2bf(v.x), f2bf(v.y), f2bf(v.z), f2bf(v.w));
}

__device__ __forceinline__ float fast_tanh(float x) {
    float e = __expf(2.0f * x);
    return 1.0f - 2.0f * __builtin_amdgcn_rcpf(e + 1.0f);
}

__device__ __forceinline__ void async16(u16* lds, const u16* g) {
    __builtin_amdgcn_global_load_lds(
        (const __attribute__((address_space(1))) void*)g,
        (__attribute__((address_space(3))) void*)lds, 16, 0, 0);
}

// ---------------- CSR build ----------------

__global__ void hist_kernel(const int* __restrict__ dst, int* __restrict__ counts) {
    int i = blockIdx.x * blockDim.x + threadIdx.x;
    if (i < E_EDGES) atomicAdd(&counts[dst[i]], 1);
}

__global__ void scan1_kernel(const int* __restrict__ counts, int* __restrict__ offsets,
                             int* __restrict__ bsum) {
    __shared__ int buf[1024];
    int t = threadIdx.x, i = blockIdx.x * 1024 + t;
    int v = (i < N_ENT) ? counts[i] : 0;
    int acc = v;
    buf[t] = acc;
    __syncthreads();
    for (int off = 1; off < 1024; off <<= 1) {
        int u = (t >= off) ? buf[t - off] : 0;
        __syncthreads();
        acc += u;
        buf[t] = acc;
        __syncthreads();
    }
    if (i < N_ENT) offsets[i] = acc - v;  // exclusive within block
    if (t == 1023) bsum[blockIdx.x] = acc;
}

__global__ void scan2_kernel(int* __restrict__ bsum, int* __restrict__ offsets) {
    __shared__ int s[128];
    int t = threadIdx.x;
    s[t] = (t < 98) ? bsum[t] : 0;
    __syncthreads();
    if (t == 0) {
        int run = 0;
        for (int b = 0; b < 98; ++b) { int x = s[b]; s[b] = run; run += x; }
        offsets[N_ENT] = run;
    }
    __syncthreads();
    if (t < 98) bsum[t] = s[t];
}

__global__ void scan3_kernel(int* __restrict__ offsets, const int* __restrict__ bsum) {
    int i = blockIdx.x * 1024 + threadIdx.x;
    if (i < N_ENT && blockIdx.x > 0) offsets[i] += bsum[blockIdx.x];
}

// CSR placement; pre-gather per-edge data into CSR order:
//   s_ridloc[pos] = rel_id | ((dst&15)<<16) ; s_sidrow[pos] = node_id[src]
__global__ void place_kernel(const int* __restrict__ dst, const int* __restrict__ src,
                             const int* __restrict__ rel_id, const int* __restrict__ node_id,
                             const int* __restrict__ offsets,
                             int* __restrict__ counts, int* __restrict__ s_ridloc,
                             int* __restrict__ s_sidrow) {
    int i = blockIdx.x * blockDim.x + threadIdx.x;
    if (i < E_EDGES) {
        int d = dst[i];
        int old = atomicSub(&counts[d], 1);
        int pos = offsets[d] + old - 1;
        s_ridloc[pos] = rel_id[i] | ((d & 15) << 16);
        s_sidrow[pos] = node_id[src[i]];
    }
}

// ---------------- weight prep ----------------
// B-fragment order for mfma_f32_16x16x32_bf16:
// dst[((ntile*8+kstep)*64+lane)*8+j] = bf16(W[kstep*32+(lane>>4)*8+j][ntile*16+(lane&15)])
__global__ void swz_kernel(const float* __restrict__ w0, const float* __restrict__ w1,
                           const float* __restrict__ w2, const float* __restrict__ w3,
                           u16* __restrict__ dstp) {
    int t = blockIdx.x * blockDim.x + threadIdx.x;
    if (t >= 4 * H * H) return;
    int mat = t >> 16;
    int r = t & 65535;
    int j = r & 7, lane = (r >> 3) & 63, kstep = (r >> 9) & 7, ntile = r >> 12;
    int k = kstep * 32 + (lane >> 4) * 8 + j;
    int n = ntile * 16 + (lane & 15);
    const float* W = (mat == 0) ? w0 : (mat == 1) ? w1 : (mat == 2) ? w2 : w3;
    dstp[t] = f2bf(W[k * H + n]);
}

// rel_emb -> bf16 A-fragment-tiled
__global__ void relbf_kernel(const float* __restrict__ rel, u16* __restrict__ out) {
    int t = blockIdx.x * blockDim.x + threadIdx.x;
    if (t >= REL_TILES * TILE_SH) return;
    int j = t & 7, lane = (t >> 3) & 63, ks = (t >> 9) & 7, tile = t >> 12;
    int m = lane & 15, quad = lane >> 4;
    int row = tile * 16 + m, k = ks * 32 + quad * 8 + j;
    float v = (row < N_REL2) ? rel[row * H + k] : 0.f;
    out[t] = f2bf(v);
}

// ---------------- fused scores + softmax + segment-sum, tile-per-block ----------------
// block = 1024 thr = one 16-dst tile. Pass 1: edge-parallel scores (16 lanes/edge,
// 4 edges in flight per wave). Pass 2: wave-per-dst softmax + weighted accumulate
// (gathers L2-warm from pass 1). Store: LDS-staged coalesced fragment-tile write.
__global__ __launch_bounds__(1024, 8) void scatter_kernel(
    const float* __restrict__ ent, const float* __restrict__ rel,
    const int* __restrict__ node_id, const int* __restrict__ offsets,
    const int* __restrict__ s_ridloc, const int* __restrict__ s_sidrow,
    u16* __restrict__ agg_e, u16* __restrict__ agg_n, u16* __restrict__ agg_c) {
    __shared__ float hd_t[16][260];   // +4 float pad: breaks bank aliasing across rows
    __shared__ float sw[3][MAXE];     // scores then weights
    __shared__ u16 outb[3][4096];     // staged output tile (fragment layout)
    int tid = threadIdx.x;
    int wv = tid >> 6, lane = tid & 63;
    int g = lane >> 4, cl = lane & 15;
    int d0 = blockIdx.x * 16;

    // preload destination rows (wave wv -> row wv), coalesced 1KB each
    {
        int nid = node_id[d0 + wv];
        float4 h4 = ((const float4*)(ent + (size_t)nid * H))[lane];
        *(float4*)&hd_t[wv][lane * 4] = h4;
    }
    int P0 = offsets[d0];
    int P1 = offsets[d0 + 16];
    int EB = P1 - P0; if (EB > MAXE) EB = MAXE;
    __syncthreads();

    // ---- pass 1: scores (edge-parallel) ----
    for (int pb = wv * 4 + g; pb < EB; pb += 64) {
        int p = P0 + pb;
        int rr = s_ridloc[p];
        int srow = s_sidrow[p];
        int rid = rr & 0xFFFF, dloc = rr >> 16;
        const float4* e4p = (const float4*)(rel + (size_t)rid * H);
        const float4* s4p = (const float4*)(ent + (size_t)srow * H);
        float de = 0.f, dn = 0.f, dc = 0.f;
#pragma unroll
        for (int q = 0; q < 4; ++q) {
            float4 e4 = e4p[cl * 4 + q];
            float4 s4 = s4p[cl * 4 + q];
            float4 h4 = *(const float4*)&hd_t[dloc][cl * 16 + q * 4];
            de += e4.x * h4.x + e4.y * h4.y + e4.z * h4.z + e4.w * h4.w;
            dn += s4.x * h4.x + s4.y * h4.y + s4.z * h4.z + s4.w * h4.w;
            dc += e4.x * s4.x * h4.x + e4.y * s4.y * h4.y + e4.z * s4.z * h4.z + e4.w * s4.w * h4.w;
        }
#pragma unroll
        for (int o = 1; o < 16; o <<= 1) {
            de += __shfl_xor(de, o);
            dn += __shfl_xor(dn, o);
            dc += __shfl_xor(dc, o);
        }
        if (cl == 0) { sw[0][pb] = de; sw[1][pb] = dn; sw[2][pb] = dc; }
    }
    __syncthreads();

    // ---- pass 2: per-dst softmax + weighted accumulation ----
    int d = d0 + wv;
    int e0 = offsets[d] - P0;
    int e1 = offsets[d + 1] - P0;
    if (e0 > EB) e0 = EB;
    if (e1 > EB) e1 = EB;
    int deg = e1 - e0; if (deg > 64) deg = 64;
    {
        float ve = -INFINITY, vn = -INFINITY, vc = -INFINITY;
        if (lane < deg) { ve = sw[0][e0 + lane]; vn = sw[1][e0 + lane]; vc = sw[2][e0 + lane]; }
        float me = ve, mn = vn, mc = vc;
#pragma unroll
        for (int o = 1; o < 64; o <<= 1) {
            me = fmaxf(me, __shfl_xor(me, o));
            mn = fmaxf(mn, __shfl_xor(mn, o));
            mc = fmaxf(mc, __shfl_xor(mc, o));
        }
        float pe = (lane < deg) ? __expf(ve - me) : 0.f;
        float pn = (lane < deg) ? __expf(vn - mn) : 0.f;
        float pc = (lane < deg) ? __expf(vc - mc) : 0.f;
        float se = pe, sn = pn, sc = pc;
#pragma unroll
        for (int o = 1; o < 64; o <<= 1) {
            se += __shfl_xor(se, o);
            sn += __shfl_xor(sn, o);
            sc += __shfl_xor(sc, o);
        }
        if (lane < deg) {
            sw[0][e0 + lane] = pe / se;
            sw[1][e0 + lane] = pn / sn;
            sw[2][e0 + lane] = pc / sc;
        }
    }

    float4 ae = make_float4(0, 0, 0, 0), an = make_float4(0, 0, 0, 0), ac = make_float4(0, 0, 0, 0);
    for (int q0 = e0; q0 < e0 + deg; q0 += 2) {
        int n = e0 + deg - q0; if (n > 2) n = 2;
        int rid[2], srow[2];
        float we[2], wn[2], wc[2];
#pragma unroll
        for (int j = 0; j < 2; ++j) if (j < n) {
            rid[j] = s_ridloc[P0 + q0 + j] & 0xFFFF;
            srow[j] = s_sidrow[P0 + q0 + j];
            we[j] = sw[0][q0 + j]; wn[j] = sw[1][q0 + j]; wc[j] = sw[2][q0 + j];
        }
        float4 e4[2], s4[2];
#pragma unroll
        for (int j = 0; j < 2; ++j) if (j < n) {
            e4[j] = ((const float4*)(rel + (size_t)rid[j] * H))[lane];
            s4[j] = ((const float4*)(ent + (size_t)srow[j] * H))[lane];
        }
#pragma unroll
        for (int j = 0; j < 2; ++j) if (j < n) {
            ae.x += we[j] * e4[j].x; ae.y += we[j] * e4[j].y;
            ae.z += we[j] * e4[j].z; ae.w += we[j] * e4[j].w;
            an.x += wn[j] * s4[j].x; an.y += wn[j] * s4[j].y;
            an.z += wn[j] * s4[j].z; an.w += wn[j] * s4[j].w;
            ac.x += wc[j] * e4[j].x * s4[j].x; ac.y += wc[j] * e4[j].y * s4[j].y;
            ac.z += wc[j] * e4[j].z * s4[j].z; ac.w += wc[j] * e4[j].w * s4[j].w;
        }
    }

    // stage into LDS in fragment-tile layout, then coalesced cooperative store
    {
        int ks = lane >> 3, q16 = (lane >> 1) & 3, j0 = (lane & 1) * 4;
        int a = (ks * 64 + q16 * 16 + wv) * 8 + j0;
        *(ushort4*)&outb[0][a] = pack4(ae);
        *(ushort4*)&outb[1][a] = pack4(an);
        *(ushort4*)&outb[2][a] = pack4(ac);
    }
    __syncthreads();
    if (tid < 512) {
        size_t gbase = (size_t)blockIdx.x * TILE_SH + tid * 8;
        *(uint4*)(agg_e + gbase) = *(const uint4*)&outb[0][tid * 8];
        *(uint4*)(agg_n + gbase) = *(const uint4*)&outb[1][tid * 8];
        *(uint4*)(agg_c + gbase) = *(const uint4*)&outb[2][tid * 8];
    }
}

// ---------------- fused multi-layer GEMM epilogue ----------------
// out[r,:] = base[r,:] + sum_l tanh(A_l[r,:] @ W_l)   (raw if !do_tanh)
// single 32KB LDS buffer -> 4 blocks/CU; cross-block overlap hides barrier drains
__global__ __launch_bounds__(256, 4) void gemm_kernel(
    const u16* __restrict__ A0, const u16* __restrict__ A1, const u16* __restrict__ A2,
    const u16* __restrict__ W0, const u16* __restrict__ W1, const u16* __restrict__ W2,
    const float* __restrict__ base, float* __restrict__ out,
    int n_real, int n_layers, int do_tanh) {
    __shared__ u16 lA[16384];  // 32KB, fragment-tiled: rt*4096 + ks*512 + lane*8
    int tid = threadIdx.x;
    int lane = tid & 63;
    int wv = tid >> 6;
    int m = lane & 15;
    int quad = lane >> 4;
    int r0 = blockIdx.x * 64;
    const u16* As[3] = { A0, A1, A2 };
    const u16* Ws[3] = { W0, W1, W2 };

    float outacc[4][4][4];
#pragma unroll
    for (int rt = 0; rt < 4; ++rt)
#pragma unroll
        for (int ct = 0; ct < 4; ++ct) {
            int grow = r0 + rt * 16 + quad * 4;
            int gcol = wv * 64 + ct * 16 + m;
#pragma unroll
            for (int r = 0; r < 4; ++r) {
                float v = 0.f;
                if (base != nullptr && (grow + r) < n_real) v = base[(size_t)(grow + r) * H + gcol];
                outacc[rt][ct][r] = v;
            }
        }

    for (int l = 0; l < n_layers; ++l) {
        __syncthreads();  // prev layer's ds_reads done before overwrite
        {
            const u16* gsrc = As[l] + (size_t)blockIdx.x * 4 * TILE_SH;
#pragma unroll
            for (int rnd = 0; rnd < 8; ++rnd) {
                int off8 = (rnd * 256 + tid) * 8;
                async16(&lA[off8], gsrc + off8);
            }
        }
        __syncthreads();  // staged
        const u16* Wl = Ws[l];

        floatx4 lacc[4][4];
#pragma unroll
        for (int rt = 0; rt < 4; ++rt)
#pragma unroll
            for (int ct = 0; ct < 4; ++ct)
#pragma unroll
                for (int r = 0; r < 4; ++r) lacc[rt][ct][r] = 0.f;

#pragma unroll
        for (int ks = 0; ks < 8; ++ks) {
            bf16x8 af[4], bfr[4];
#pragma unroll
            for (int rt = 0; rt < 4; ++rt)
                af[rt] = *(const bf16x8*)(lA + rt * 4096 + ks * 512 + lane * 8);
#pragma unroll
            for (int ct = 0; ct < 4; ++ct)
                bfr[ct] = *(const bf16x8*)(Wl + (((size_t)(wv * 4 + ct) * 8 + ks) * 64 + lane) * 8);
#pragma unroll
            for (int rt = 0; rt < 4; ++rt)
#pragma unroll
                for (int ct = 0; ct < 4; ++ct)
                    lacc[rt][ct] = __builtin_amdgcn_mfma_f32_16x16x32_bf16(
                        af[rt], bfr[ct], lacc[rt][ct], 0, 0, 0);
        }

#pragma unroll
        for (int rt = 0; rt < 4; ++rt)
#pragma unroll
            for (int ct = 0; ct < 4; ++ct)
#pragma unroll
                for (int r = 0; r < 4; ++r) {
                    float v = lacc[rt][ct][r];
                    outacc[rt][ct][r] += do_tanh ? fast_tanh(v) : v;
                }
    }

#pragma unroll
    for (int rt = 0; rt < 4; ++rt)
#pragma unroll
        for (int ct = 0; ct < 4; ++ct) {
            int grow = r0 + rt * 16 + quad * 4;
            int gcol = wv * 64 + ct * 16 + m;
#pragma unroll
            for (int r = 0; r < 4; ++r)
                if ((grow + r) < n_real) out[(size_t)(grow + r) * H + gcol] = outacc[rt][ct][r];
        }
}

// ---------------- launch ----------------

extern "C" void kernel_launch(void* const* d_in, const int* in_sizes, int n_in,
                              void* d_out, int out_size, void* d_ws, size_t ws_size,
                              hipStream_t stream) {
    (void)in_sizes; (void)n_in; (void)out_size; (void)ws_size;
    const float* ent    = (const float*)d_in[0];
    const float* rel    = (const float*)d_in[1];
    const float* w_edge = (const float*)d_in[2];
    const float* w_node = (const float*)d_in[3];
    const float* w_comp = (const float*)d_in[4];
    const float* rel_w  = (const float*)d_in[5];
    const int* src      = (const int*)d_in[6];
    const int* dst      = (const int*)d_in[7];
    const int* rel_id   = (const int*)d_in[8];
    const int* node_id  = (const int*)d_in[9];

    char* wsb = (char*)d_ws;
    size_t o = 0;
    auto alloc = [&](size_t bytes) -> char* {
        char* p = wsb + o;
        o = (o + bytes + 255) & ~(size_t)255;
        return p;
    };
    int* counts   = (int*)alloc((size_t)N_ENT * 4);
    int* offsets  = (int*)alloc((size_t)(N_ENT + 1) * 4);
    int* bsum     = (int*)alloc(128 * 4);
    int* s_ridloc = (int*)alloc((size_t)E_EDGES * 4);
    int* s_sidrow = (int*)alloc((size_t)E_EDGES * 4);
    u16* agg_e    = (u16*)alloc((size_t)N_TILES * TILE_SH * 2);
    u16* agg_n    = (u16*)alloc((size_t)N_TILES * TILE_SH * 2);
    u16* agg_c    = (u16*)alloc((size_t)N_TILES * TILE_SH * 2);
    u16* wswz     = (u16*)alloc((size_t)4 * H * H * 2);
    u16* relbf    = (u16*)alloc((size_t)REL_TILES * TILE_SH * 2);
    (void)alloc(65536);  // overrun pad for gemm tail-block A staging reads

    float* out_ent = (float*)d_out;
    float* out_rel = out_ent + (size_t)N_ENT * H;

    hipMemsetAsync(counts, 0, (size_t)N_ENT * 4, stream);
    hist_kernel<<<(E_EDGES + 255) / 256, 256, 0, stream>>>(dst, counts);
    scan1_kernel<<<98, 1024, 0, stream>>>(counts, offsets, bsum);
    scan2_kernel<<<1, 128, 0, stream>>>(bsum, offsets);
    scan3_kernel<<<98, 1024, 0, stream>>>(offsets, bsum);
    place_kernel<<<(E_EDGES + 255) / 256, 256, 0, stream>>>(dst, src, rel_id, node_id,
                                                            offsets, counts, s_ridloc, s_sidrow);
    swz_kernel<<<(4 * H * H + 255) / 256, 256, 0, stream>>>(w_edge, w_node, w_comp, rel_w, wswz);
    relbf_kernel<<<(REL_TILES * TILE_SH + 255) / 256, 256, 0, stream>>>(rel, relbf);
    scatter_kernel<<<N_TILES, 1024, 0, stream>>>(ent, rel, node_id, offsets,
                                                 s_ridloc, s_sidrow, agg_e, agg_n, agg_c);
    gemm_kernel<<<(N_ENT + 63) / 64, 256, 0, stream>>>(agg_e, agg_n, agg_c,
                                                       wswz, wswz + H * H, wswz + 2 * H * H,
                                                       ent, out_ent, N_ENT, 3, 1);
    gemm_kernel<<<(N_REL2 + 63) / 64, 256, 0, stream>>>(relbf, relbf, relbf,
                                                        wswz + 3 * H * H, wswz + 3 * H * H, wswz + 3 * H * H,
                                                        nullptr, out_rel, N_REL2, 1, 0);
}

// Round 4
// 700.228 us; speedup vs baseline: 1.0059x; 1.0059x over previous
//
#include <hip/hip_runtime.h>
#include <hip/hip_bf16.h>

#define N_ENT  100000
#define N_REL2 1000
#define H      256
#define E_EDGES 320000
#define N_TILES  6250      // N_ENT/16 exactly
#define REL_TILES 64       // ceil(1000/16)=63, pad to 64
#define TILE_SH 4096       // shorts per 16-row tile (16*256)
#define MAXE 256           // max edges per 16-dst tile (mean 51 -> huge headroom)

typedef unsigned short u16;
typedef short bf16x8 __attribute__((ext_vector_type(8)));
typedef float floatx4 __attribute__((ext_vector_type(4)));

__device__ __forceinline__ u16 f2bf(float f) {
    unsigned x = __float_as_uint(f);
    unsigned r = (x + 0x7fffu + ((x >> 16) & 1u)) >> 16;  // RNE
    return (u16)r;
}

__device__ __forceinline__ float bf2f(u16 s) {
    return __uint_as_float(((unsigned)s) << 16);
}

__device__ __forceinline__ ushort4 pack4(float4 v) {
    return make_ushort4(f2bf(v.x), f2bf(v.y), f2bf(v.z), f2bf(v.w));
}

__device__ __forceinline__ float fast_tanh(float x) {
    float e = __expf(2.0f * x);
    return 1.0f - 2.0f * __builtin_amdgcn_rcpf(e + 1.0f);
}

// ---------------- CSR build ----------------

__global__ void hist_kernel(const int* __restrict__ dst, int* __restrict__ counts) {
    int i = blockIdx.x * blockDim.x + threadIdx.x;
    if (i < E_EDGES) atomicAdd(&counts[dst[i]], 1);
}

__global__ void scan1_kernel(const int* __restrict__ counts, int* __restrict__ offsets,
                             int* __restrict__ bsum) {
    __shared__ int buf[1024];
    int t = threadIdx.x, i = blockIdx.x * 1024 + t;
    int v = (i < N_ENT) ? counts[i] : 0;
    int acc = v;
    buf[t] = acc;
    __syncthreads();
    for (int off = 1; off < 1024; off <<= 1) {
        int u = (t >= off) ? buf[t - off] : 0;
        __syncthreads();
        acc += u;
        buf[t] = acc;
        __syncthreads();
    }
    if (i < N_ENT) offsets[i] = acc - v;  // exclusive within block
    if (t == 1023) bsum[blockIdx.x] = acc;
}

__global__ void scan2_kernel(int* __restrict__ bsum, int* __restrict__ offsets) {
    __shared__ int s[128];
    int t = threadIdx.x;
    s[t] = (t < 98) ? bsum[t] : 0;
    __syncthreads();
    if (t == 0) {
        int run = 0;
        for (int b = 0; b < 98; ++b) { int x = s[b]; s[b] = run; run += x; }
        offsets[N_ENT] = run;
    }
    __syncthreads();
    if (t < 98) bsum[t] = s[t];
}

__global__ void scan3_kernel(int* __restrict__ offsets, const int* __restrict__ bsum) {
    int i = blockIdx.x * 1024 + threadIdx.x;
    if (i < N_ENT && blockIdx.x > 0) offsets[i] += bsum[blockIdx.x];
}

// CSR placement; pre-gather per-edge data into CSR order:
//   s_ridloc[pos] = rel_id | ((dst&15)<<16) ; s_sidrow[pos] = node_id[src]
__global__ void place_kernel(const int* __restrict__ dst, const int* __restrict__ src,
                             const int* __restrict__ rel_id, const int* __restrict__ node_id,
                             const int* __restrict__ offsets,
                             int* __restrict__ counts, int* __restrict__ s_ridloc,
                             int* __restrict__ s_sidrow) {
    int i = blockIdx.x * blockDim.x + threadIdx.x;
    if (i < E_EDGES) {
        int d = dst[i];
        int old = atomicSub(&counts[d], 1);
        int pos = offsets[d] + old - 1;
        s_ridloc[pos] = rel_id[i] | ((d & 15) << 16);
        s_sidrow[pos] = node_id[src[i]];
    }
}

// ---------------- weight + rel prep (merged) ----------------
// wswz: B-fragment order for mfma_f32_16x16x32_bf16:
//   dst[((nt*8+ks)*64+lane)*8+j] = bf16(W[ks*32+(lane>>4)*8+j][nt*16+(lane&15)])
// relbf: rel_emb -> bf16 A-fragment-tiled (16-row tiles, zero-padded to 64 tiles)
__global__ void prep_kernel(const float* __restrict__ w0, const float* __restrict__ w1,
                            const float* __restrict__ w2, const float* __restrict__ w3,
                            const float* __restrict__ rel,
                            u16* __restrict__ wswz, u16* __restrict__ relbf) {
    int t = blockIdx.x * blockDim.x + threadIdx.x;
    if (t < 4 * H * H) {
        int mat = t >> 16;
        int r = t & 65535;
        int j = r & 7, lane = (r >> 3) & 63, ks = (r >> 9) & 7, nt = r >> 12;
        int k = ks * 32 + (lane >> 4) * 8 + j;
        int n = nt * 16 + (lane & 15);
        const float* W = (mat == 0) ? w0 : (mat == 1) ? w1 : (mat == 2) ? w2 : w3;
        wswz[t] = f2bf(W[k * H + n]);
    } else {
        int t2 = t - 4 * H * H;
        if (t2 < REL_TILES * TILE_SH) {
            int j = t2 & 7, lane = (t2 >> 3) & 63, ks = (t2 >> 9) & 7, tile = t2 >> 12;
            int m = lane & 15, quad = lane >> 4;
            int row = tile * 16 + m, k = ks * 32 + quad * 8 + j;
            float v = (row < N_REL2) ? rel[row * H + k] : 0.f;
            relbf[t2] = f2bf(v);
        }
    }
}

// ---------------- fused scores + softmax + segment-sum, tile-per-block ----------------
__global__ __launch_bounds__(1024, 8) void scatter_kernel(
    const float* __restrict__ ent, const float* __restrict__ rel,
    const int* __restrict__ node_id, const int* __restrict__ offsets,
    const int* __restrict__ s_ridloc, const int* __restrict__ s_sidrow,
    u16* __restrict__ agg_e, u16* __restrict__ agg_n, u16* __restrict__ agg_c) {
    __shared__ float hd_t[16][260];
    __shared__ float sw[3][MAXE];
    __shared__ u16 outb[3][4096];
    int tid = threadIdx.x;
    int wv = tid >> 6, lane = tid & 63;
    int g = lane >> 4, cl = lane & 15;
    int d0 = blockIdx.x * 16;

    {
        int nid = node_id[d0 + wv];
        float4 h4 = ((const float4*)(ent + (size_t)nid * H))[lane];
        *(float4*)&hd_t[wv][lane * 4] = h4;
    }
    int P0 = offsets[d0];
    int P1 = offsets[d0 + 16];
    int EB = P1 - P0; if (EB > MAXE) EB = MAXE;
    __syncthreads();

    // pass 1: edge-parallel scores (16 lanes/edge)
    for (int pb = wv * 4 + g; pb < EB; pb += 64) {
        int p = P0 + pb;
        int rr = s_ridloc[p];
        int srow = s_sidrow[p];
        int rid = rr & 0xFFFF, dloc = rr >> 16;
        const float4* e4p = (const float4*)(rel + (size_t)rid * H);
        const float4* s4p = (const float4*)(ent + (size_t)srow * H);
        float de = 0.f, dn = 0.f, dc = 0.f;
#pragma unroll
        for (int q = 0; q < 4; ++q) {
            float4 e4 = e4p[cl * 4 + q];
            float4 s4 = s4p[cl * 4 + q];
            float4 h4 = *(const float4*)&hd_t[dloc][cl * 16 + q * 4];
            de += e4.x * h4.x + e4.y * h4.y + e4.z * h4.z + e4.w * h4.w;
            dn += s4.x * h4.x + s4.y * h4.y + s4.z * h4.z + s4.w * h4.w;
            dc += e4.x * s4.x * h4.x + e4.y * s4.y * h4.y + e4.z * s4.z * h4.z + e4.w * s4.w * h4.w;
        }
#pragma unroll
        for (int o = 1; o < 16; o <<= 1) {
            de += __shfl_xor(de, o);
            dn += __shfl_xor(dn, o);
            dc += __shfl_xor(dc, o);
        }
        if (cl == 0) { sw[0][pb] = de; sw[1][pb] = dn; sw[2][pb] = dc; }
    }
    __syncthreads();

    // pass 2: per-dst softmax + weighted accumulation
    int d = d0 + wv;
    int e0 = offsets[d] - P0;
    int e1 = offsets[d + 1] - P0;
    if (e0 > EB) e0 = EB;
    if (e1 > EB) e1 = EB;
    int deg = e1 - e0; if (deg > 64) deg = 64;
    {
        float ve = -INFINITY, vn = -INFINITY, vc = -INFINITY;
        if (lane < deg) { ve = sw[0][e0 + lane]; vn = sw[1][e0 + lane]; vc = sw[2][e0 + lane]; }
        float me = ve, mn = vn, mc = vc;
#pragma unroll
        for (int o = 1; o < 64; o <<= 1) {
            me = fmaxf(me, __shfl_xor(me, o));
            mn = fmaxf(mn, __shfl_xor(mn, o));
            mc = fmaxf(mc, __shfl_xor(mc, o));
        }
        float pe = (lane < deg) ? __expf(ve - me) : 0.f;
        float pn = (lane < deg) ? __expf(vn - mn) : 0.f;
        float pc = (lane < deg) ? __expf(vc - mc) : 0.f;
        float se = pe, sn = pn, sc = pc;
#pragma unroll
        for (int o = 1; o < 64; o <<= 1) {
            se += __shfl_xor(se, o);
            sn += __shfl_xor(sn, o);
            sc += __shfl_xor(sc, o);
        }
        if (lane < deg) {
            sw[0][e0 + lane] = pe / se;
            sw[1][e0 + lane] = pn / sn;
            sw[2][e0 + lane] = pc / sc;
        }
    }

    float4 ae = make_float4(0, 0, 0, 0), an = make_float4(0, 0, 0, 0), ac = make_float4(0, 0, 0, 0);
    for (int q0 = e0; q0 < e0 + deg; q0 += 2) {
        int n = e0 + deg - q0; if (n > 2) n = 2;
        int rid[2], srow[2];
        float we[2], wn[2], wc[2];
#pragma unroll
        for (int j = 0; j < 2; ++j) if (j < n) {
            rid[j] = s_ridloc[P0 + q0 + j] & 0xFFFF;
            srow[j] = s_sidrow[P0 + q0 + j];
            we[j] = sw[0][q0 + j]; wn[j] = sw[1][q0 + j]; wc[j] = sw[2][q0 + j];
        }
        float4 e4[2], s4[2];
#pragma unroll
        for (int j = 0; j < 2; ++j) if (j < n) {
            e4[j] = ((const float4*)(rel + (size_t)rid[j] * H))[lane];
            s4[j] = ((const float4*)(ent + (size_t)srow[j] * H))[lane];
        }
#pragma unroll
        for (int j = 0; j < 2; ++j) if (j < n) {
            ae.x += we[j] * e4[j].x; ae.y += we[j] * e4[j].y;
            ae.z += we[j] * e4[j].z; ae.w += we[j] * e4[j].w;
            an.x += wn[j] * s4[j].x; an.y += wn[j] * s4[j].y;
            an.z += wn[j] * s4[j].z; an.w += wn[j] * s4[j].w;
            ac.x += wc[j] * e4[j].x * s4[j].x; ac.y += wc[j] * e4[j].y * s4[j].y;
            ac.z += wc[j] * e4[j].z * s4[j].z; ac.w += wc[j] * e4[j].w * s4[j].w;
        }
    }

    {
        int ks = lane >> 3, q16 = (lane >> 1) & 3, j0 = (lane & 1) * 4;
        int a = (ks * 64 + q16 * 16 + wv) * 8 + j0;
        *(ushort4*)&outb[0][a] = pack4(ae);
        *(ushort4*)&outb[1][a] = pack4(an);
        *(ushort4*)&outb[2][a] = pack4(ac);
    }
    __syncthreads();
    if (tid < 512) {
        size_t gbase = (size_t)blockIdx.x * TILE_SH + tid * 8;
        *(uint4*)(agg_e + gbase) = *(const uint4*)&outb[0][tid * 8];
        *(uint4*)(agg_n + gbase) = *(const uint4*)&outb[1][tid * 8];
        *(uint4*)(agg_c + gbase) = *(const uint4*)&outb[2][tid * 8];
    }
}

// ---------------- wave-independent fused 3-layer GEMM + residual ----------------
// one wave = one 16-row tile, all 3 layers; NO barriers anywhere.
// out[r,:] = ent[r,:] + sum_l tanh(A_l[r,:] @ W_l)
// A-frags (3 layers x 8 ksteps) preloaded; B from L2; per col-tile: sum += tanh(acc).
// Output transposed via per-wave-private LDS (bf16, stride 264 -> 2-way = free),
// read back coalesced, residual added, stored row-major 32B/lane.
__global__ __launch_bounds__(256, 3) void fgemm_kernel(
    const u16* __restrict__ agg_e, const u16* __restrict__ agg_n, const u16* __restrict__ agg_c,
    const u16* __restrict__ wswz, const float* __restrict__ ent, float* __restrict__ out) {
    __shared__ u16 tb[4][16 * 264];   // 33 KB/block, per-wave private regions
    int tid = threadIdx.x, wv = tid >> 6, lane = tid & 63;
    int tile = blockIdx.x * 4 + wv;
    if (tile >= N_TILES) return;      // whole-wave exit; no barriers in kernel
    int m = lane & 15, quad = lane >> 4;

    bf16x8 af[3][8];                  // 96 VGPR: A-frags for all 3 layers
    {
        size_t abase = (size_t)tile * 4096 + lane * 8;
#pragma unroll
        for (int ks = 0; ks < 8; ++ks) {
            af[0][ks] = *(const bf16x8*)(agg_e + abase + ks * 512);
            af[1][ks] = *(const bf16x8*)(agg_n + abase + ks * 512);
            af[2][ks] = *(const bf16x8*)(agg_c + abase + ks * 512);
        }
    }
    u16* myb = tb[wv];

    for (int nt = 0; nt < 16; ++nt) {
        floatx4 sum = {0.f, 0.f, 0.f, 0.f};
#pragma unroll
        for (int l = 0; l < 3; ++l) {
            const u16* wb = wswz + (size_t)l * H * H + (size_t)nt * 4096 + lane * 8;
            floatx4 acc = {0.f, 0.f, 0.f, 0.f};
#pragma unroll
            for (int ks = 0; ks < 8; ++ks) {
                bf16x8 bfv = *(const bf16x8*)(wb + ks * 512);
                acc = __builtin_amdgcn_mfma_f32_16x16x32_bf16(af[l][ks], bfv, acc, 0, 0, 0);
            }
#pragma unroll
            for (int r = 0; r < 4; ++r) sum[r] += fast_tanh(acc[r]);
        }
#pragma unroll
        for (int r = 0; r < 4; ++r)
            myb[(quad * 4 + r) * 264 + nt * 16 + m] = f2bf(sum[r]);
    }

    // transpose read-back + residual + row-major store (2 rows / instr, 1KB coalesced)
#pragma unroll
    for (int j = 0; j < 8; ++j) {
        int r2 = j * 2 + (lane >> 5);
        int off = (lane & 31) * 8;
        size_t gaddr = ((size_t)tile * 16 + r2) * H + off;
        uint4 sv = *(const uint4*)(myb + r2 * 264 + off);
        const u16* sp = (const u16*)&sv;
        float4 e0 = *(const float4*)(ent + gaddr);
        float4 e1 = *(const float4*)(ent + gaddr + 4);
        float4 o0, o1;
        o0.x = e0.x + bf2f(sp[0]); o0.y = e0.y + bf2f(sp[1]);
        o0.z = e0.z + bf2f(sp[2]); o0.w = e0.w + bf2f(sp[3]);
        o1.x = e1.x + bf2f(sp[4]); o1.y = e1.y + bf2f(sp[5]);
        o1.z = e1.z + bf2f(sp[6]); o1.w = e1.w + bf2f(sp[7]);
        *(float4*)(out + gaddr) = o0;
        *(float4*)(out + gaddr + 4) = o1;
    }
}

// ---------------- rel GEMM: out_rel = rel_emb @ rel_w (fp32, no tanh/base) ----------------
__global__ __launch_bounds__(256, 2) void relg_kernel(
    const u16* __restrict__ relbf, const u16* __restrict__ wrel, float* __restrict__ out_rel) {
    __shared__ float tb[4][16 * 260];
    int tid = threadIdx.x, wv = tid >> 6, lane = tid & 63;
    int tile = blockIdx.x * 4 + wv;
    if (tile >= REL_TILES) return;
    int m = lane & 15, quad = lane >> 4;
    bf16x8 af[8];
    {
        size_t abase = (size_t)tile * 4096 + lane * 8;
#pragma unroll
        for (int ks = 0; ks < 8; ++ks) af[ks] = *(const bf16x8*)(relbf + abase + ks * 512);
    }
    float* myb = tb[wv];
    for (int nt = 0; nt < 16; ++nt) {
        const u16* wb = wrel + (size_t)nt * 4096 + lane * 8;
        floatx4 acc = {0.f, 0.f, 0.f, 0.f};
#pragma unroll
        for (int ks = 0; ks < 8; ++ks)
            acc = __builtin_amdgcn_mfma_f32_16x16x32_bf16(af[ks], *(const bf16x8*)(wb + ks * 512),
                                                          acc, 0, 0, 0);
#pragma unroll
        for (int r = 0; r < 4; ++r) myb[(quad * 4 + r) * 260 + nt * 16 + m] = acc[r];
    }
    for (int j = 0; j < 16; ++j) {
        int row = tile * 16 + j;
        if (row < N_REL2) {
            float4 v = *(const float4*)(myb + j * 260 + lane * 4);
            *(float4*)(out_rel + (size_t)row * H + lane * 4) = v;
        }
    }
}

// ---------------- launch ----------------

extern "C" void kernel_launch(void* const* d_in, const int* in_sizes, int n_in,
                              void* d_out, int out_size, void* d_ws, size_t ws_size,
                              hipStream_t stream) {
    (void)in_sizes; (void)n_in; (void)out_size; (void)ws_size;
    const float* ent    = (const float*)d_in[0];
    const float* rel    = (const float*)d_in[1];
    const float* w_edge = (const float*)d_in[2];
    const float* w_node = (const float*)d_in[3];
    const float* w_comp = (const float*)d_in[4];
    const float* rel_w  = (const float*)d_in[5];
    const int* src      = (const int*)d_in[6];
    const int* dst      = (const int*)d_in[7];
    const int* rel_id   = (const int*)d_in[8];
    const int* node_id  = (const int*)d_in[9];

    char* wsb = (char*)d_ws;
    size_t o = 0;
    auto alloc = [&](size_t bytes) -> char* {
        char* p = wsb + o;
        o = (o + bytes + 255) & ~(size_t)255;
        return p;
    };
    int* counts   = (int*)alloc((size_t)N_ENT * 4);
    int* offsets  = (int*)alloc((size_t)(N_ENT + 1) * 4);
    int* bsum     = (int*)alloc(128 * 4);
    int* s_ridloc = (int*)alloc((size_t)E_EDGES * 4);
    int* s_sidrow = (int*)alloc((size_t)E_EDGES * 4);
    u16* agg_e    = (u16*)alloc((size_t)N_TILES * TILE_SH * 2);
    u16* agg_n    = (u16*)alloc((size_t)N_TILES * TILE_SH * 2);
    u16* agg_c    = (u16*)alloc((size_t)N_TILES * TILE_SH * 2);
    u16* wswz     = (u16*)alloc((size_t)4 * H * H * 2);
    u16* relbf    = (u16*)alloc((size_t)REL_TILES * TILE_SH * 2);

    float* out_ent = (float*)d_out;
    float* out_rel = out_ent + (size_t)N_ENT * H;

    hipMemsetAsync(counts, 0, (size_t)N_ENT * 4, stream);
    hist_kernel<<<(E_EDGES + 255) / 256, 256, 0, stream>>>(dst, counts);
    scan1_kernel<<<98, 1024, 0, stream>>>(counts, offsets, bsum);
    scan2_kernel<<<1, 128, 0, stream>>>(bsum, offsets);
    scan3_kernel<<<98, 1024, 0, stream>>>(offsets, bsum);
    place_kernel<<<(E_EDGES + 255) / 256, 256, 0, stream>>>(dst, src, rel_id, node_id,
                                                            offsets, counts, s_ridloc, s_sidrow);
    prep_kernel<<<2048, 256, 0, stream>>>(w_edge, w_node, w_comp, rel_w, rel, wswz, relbf);
    scatter_kernel<<<N_TILES, 1024, 0, stream>>>(ent, rel, node_id, offsets,
                                                 s_ridloc, s_sidrow, agg_e, agg_n, agg_c);
    fgemm_kernel<<<(N_TILES + 3) / 4, 256, 0, stream>>>(agg_e, agg_n, agg_c, wswz, ent, out_ent);
    relg_kernel<<<REL_TILES / 4, 256, 0, stream>>>(relbf, wswz + 3 * H * H, out_rel);
}